// Round 3
// baseline (78.856 us; speedup 1.0000x reference)
//
#include <hip/hip_runtime.h>

#define N_KPS 1024
#define N_PTS 120000
#define BLOCK 512                  // 8 waves per block
#define KSPLIT 8                   // one wave per K-chunk
#define KCHUNK (N_KPS / KSPLIT)    // 128 control points per wave
#define PTS_PER_THREAD 4
#define PTS_PER_BLOCK 256          // 64 lanes x 4 points/thread
#define CHUNK 8                    // ctrl points per chunk
#define NCHUNK (KCHUNK / CHUNK)    // 16

typedef float v2f __attribute__((ext_vector_type(2)));

// r3: readfirstlane wave id -> SGPR -> kps/W become s_load (scalar broadcast).
// r6: full unroll + fma-folded epsilon: 82.4 -> 78.3 (-4.1us). Partial confirm
//     of issue-bound theory; kernel half now ~38us vs ~15us exec floor.
// r7 (this round): remaining gap blamed on per-chunk scalar-load latency
// exposure: SGPR budget caps lookahead at ~2 chunks; chunk compute body
// (~220cyc, 8 evals x 2pts) < s_load L2 latency (~300cyc). Fix: 4 pts/thread.
// Same 2 s_load_dwordx16 per chunk now feed ~450cyc of compute -> latency
// hidden within one wave; ctrl fetch per unit work halves; 32 logs in flight.
// Grid 469 blocks -> 3.66 waves/SIMD needed, so VGPR up to ~128 costs nothing.
// Prediction: dur 78.3 -> 66-69. Flat => exec-bound, pivot to packed-math.
__global__ __launch_bounds__(BLOCK) void tps_warp_kernel(
    const float2* __restrict__ pts,
    const float*  __restrict__ kps,
    const float*  __restrict__ W,
    float2*       __restrict__ out)
{
    // part[set][wv][lane]: set 0 = points {0,1}, set 1 = points {2,3}.
    __shared__ float4 part[2][KSPLIT][64];

    const int lane = threadIdx.x & 63;
    // Provably wave-uniform wave id -> SGPR -> scalar loads for kps/W.
    const int wv = __builtin_amdgcn_readfirstlane(threadIdx.x) >> 6;

    const int base = blockIdx.x * PTS_PER_BLOCK;
    const int j0 = base + 0 * 64 + lane;
    const int j1 = base + 1 * 64 + lane;
    const int j2 = base + 2 * 64 + lane;
    const int j3 = base + 3 * 64 + lane;
    const float2 p0 = pts[j0 < N_PTS ? j0 : N_PTS - 1];
    const float2 p1 = pts[j1 < N_PTS ? j1 : N_PTS - 1];
    const float2 p2 = pts[j2 < N_PTS ? j2 : N_PTS - 1];
    const float2 p3 = pts[j3 < N_PTS ? j3 : N_PTS - 1];

    v2f pxA = {p0.x, p1.x}, pyA = {p0.y, p1.y};
    v2f pxB = {p2.x, p3.x}, pyB = {p2.y, p3.y};
    v2f zxA = {0.f, 0.f}, zyA = {0.f, 0.f};
    v2f zxB = {0.f, 0.f}, zyB = {0.f, 0.f};
    const v2f tiny = {1e-37f, 1e-37f};

    auto eval = [&](float kx, float ky, float wx, float wy) {
        const v2f kxx = {kx, kx}, kyy = {ky, ky};
        const v2f wxx = {wx, wx}, wyy = {wy, wy};
        v2f dxA = kxx - pxA, dyA = kyy - pyA;
        v2f dxB = kxx - pxB, dyB = kyy - pyB;
        // Epsilon folded into the chain: d2 >= 1e-37, no v_max; d2==0 case
        // gives 1e-37*log2(1e-37) ~ -1e-35 ~ 0 == reference where(l2==0,1)->0.
        v2f d2A = __builtin_elementwise_fma(
            dyA, dyA, __builtin_elementwise_fma(dxA, dxA, tiny));
        v2f d2B = __builtin_elementwise_fma(
            dyB, dyB, __builtin_elementwise_fma(dxB, dxB, tiny));
        v2f tA, tB;
        tA.x = __log2f(d2A.x);
        tA.y = __log2f(d2A.y);
        tB.x = __log2f(d2B.x);
        tB.y = __log2f(d2B.y);
        v2f vA = d2A * tA;                   // 0.5*ln2 folded in at the end
        v2f vB = d2B * tB;
        zxA = __builtin_elementwise_fma(vA, wxx, zxA);
        zyA = __builtin_elementwise_fma(vA, wyy, zyA);
        zxB = __builtin_elementwise_fma(vB, wxx, zxB);
        zyB = __builtin_elementwise_fma(vB, wyy, zyB);
    };

    // float4 view of ctrl data: kp4[t] = {k[2t].x, k[2t].y, k[2t+1].x, k[2t+1].y}
    // (two ctrl points per float4); same for wp4.
    const float4* __restrict__ kp4 = (const float4*)kps;   // 512 entries
    const float4* __restrict__ wp4 = (const float4*)W;
    const int cbase = wv * (KCHUNK / 2);                   // float4 index base

    // Fully unrolled: s_loads schedule chunks ahead; 32 evals in flight per
    // chunk give ~450cyc compute body per 2 s_load_dwordx16.
    #pragma unroll
    for (int c = 0; c < NCHUNK; ++c) {
        float4 kc[4], wc[4];
        #pragma unroll
        for (int t = 0; t < 4; ++t) {
            kc[t] = kp4[cbase + c * 4 + t];
            wc[t] = wp4[cbase + c * 4 + t];
        }
        #pragma unroll
        for (int t = 0; t < 4; ++t) {
            eval(kc[t].x, kc[t].y, wc[t].x, wc[t].y);
            eval(kc[t].z, kc[t].w, wc[t].z, wc[t].w);
        }
    }

    part[0][wv][lane] = make_float4(zxA.x, zyA.x, zxA.y, zyA.y);
    part[1][wv][lane] = make_float4(zxB.x, zyB.x, zxB.y, zyB.y);
    __syncthreads();

    // Tail: waves 0..3 each finalize one point set. All selects use
    // compile-time indices (no dynamically-indexed per-thread arrays).
    if (wv < 4) {
        const bool hiHalf = (wv & 1);        // pick .z/.w vs .x/.y
        const int setB = (wv >> 1);          // pick part[1] vs part[0]
        const float2 p = (wv == 0) ? p0 : (wv == 1) ? p1 : (wv == 2) ? p2 : p3;
        const int j   = (wv == 0) ? j0 : (wv == 1) ? j1 : (wv == 2) ? j2 : j3;

        float sx = 0.f, sy = 0.f;
        #pragma unroll
        for (int w = 0; w < KSPLIT; ++w) {
            float4 a = part[setB][w][lane];
            sx += hiHalf ? a.z : a.x;
            sy += hiHalf ? a.w : a.y;
        }

        const float scale = 0.34657359027997264f;  // 0.5 * ln(2)
        float w1x = W[2048], w1y = W[2049];
        float wxx = W[2050], wxy = W[2051];
        float wyx = W[2052], wyy = W[2053];

        if (j < N_PTS) {
            float ox = p.x + fmaf(scale, sx, fmaf(wxx, p.x, fmaf(wyx, p.y, w1x)));
            float oy = p.y + fmaf(scale, sy, fmaf(wxy, p.x, fmaf(wyy, p.y, w1y)));
            out[j] = make_float2(ox, oy);
        }
    }
}

extern "C" void kernel_launch(void* const* d_in, const int* in_sizes, int n_in,
                              void* d_out, int out_size, void* d_ws, size_t ws_size,
                              hipStream_t stream) {
    const float* pts = (const float*)d_in[0];   // [120000, 2]
    const float* kps = (const float*)d_in[1];   // [1024, 2]
    const float* W   = (const float*)d_in[2];   // [1027, 2]
    float* out = (float*)d_out;                 // [120000, 2]

    const int grid = (N_PTS + PTS_PER_BLOCK - 1) / PTS_PER_BLOCK;  // 469
    tps_warp_kernel<<<grid, BLOCK, 0, stream>>>(
        (const float2*)pts, kps, W, (float2*)out);
}